// Round 9
// baseline (97.315 us; speedup 1.0000x reference)
//
#include <hip/hip_runtime.h>
#include <hip/hip_bf16.h>

#define BATCH 131072
#define PITCH_H 72   // half-tile row: 64 + 8 pad bf16 (144 B), keeps 16B align

typedef __bf16 bf16x8 __attribute__((ext_vector_type(8)));
typedef float floatx4 __attribute__((ext_vector_type(4)));

__device__ __forceinline__ float fast_tanh(float x) {
    // tanh(x) = 1 - 2/(exp(2x)+1); exp overflow -> inf -> rcp -> 0 -> +1 (correct limit)
    float e = __expf(2.0f * x);
    return 1.0f - 2.0f * __builtin_amdgcn_rcpf(e + 1.0f);
}

// d_ws element layout (bf16):
// [0,16384)       W2s : B-frag swizzled W2              (GEMM1: h2pre = h1 @ W2)
// [16384,32768)   GTs : B-frag swizzled G^T, G=W2*C^T   (GEMM2: U = a2 @ G^T)
// [32768,36864)   W1s : B-frag swizzled W1, K pad to 32 (GEMM0: h1pre = [z|t] @ W1)
// [36864,38912)   W3s : B-frag swizzled W3, N pad to 16 (GEMM3: dz = h2 @ W3)
// swizzle: idx = ((kb*N + n)*4 + q)*8 + j  <->  B[k = kb*32 + q*8 + j][n]

__global__ void prep_kernel(const float* __restrict__ W1,
                            const float* __restrict__ W2,
                            const float* __restrict__ W3,
                            __bf16* __restrict__ ws) {
    int idx = blockIdx.x * 256 + threadIdx.x;
    if (idx < 16384) {
        int j = idx & 7, q = (idx >> 3) & 3, n = (idx >> 5) & 127, kb = idx >> 12;
        int k = kb * 32 + q * 8 + j;
        ws[idx] = (__bf16)W2[k * 128 + n];
        float c = 0.0f;
        #pragma unroll
        for (int d = 0; d < 8; ++d) c += W3[k * 8 + d] * W1[d * 128 + n];
        ws[16384 + idx] = (__bf16)(W2[n * 128 + k] * c);
    } else if (idx < 20480) {
        int t = idx - 16384;
        int j = t & 7, q = (t >> 3) & 3, n = t >> 5;   // kb==0 only
        int k = q * 8 + j;
        ws[32768 + t] = (k < 9) ? (__bf16)W1[k * 128 + n] : (__bf16)0.0f;
    } else if (idx < 22528) {
        int t = idx - 20480;
        int j = t & 7, q = (t >> 3) & 3, n = (t >> 5) & 15, kb = t >> 9;
        int k = kb * 32 + q * 8 + j;
        ws[36864 + t] = (n < 8) ? (__bf16)W3[k * 8 + n] : (__bf16)0.0f;
    }
}

// ---- per-group phases (forceinline'd; all indices compile-time) ----

__device__ __forceinline__ void phase0_h1(
        const bf16x8& ax, const bf16x8* w1f, const float* sb1,
        __bf16* T, int p, int q, float* a1c, bf16x8* ah) {
    #pragma unroll
    for (int half = 0; half < 2; ++half) {
        #pragma unroll
        for (int lt = 0; lt < 4; ++lt) {
            const int nt = half * 4 + lt;
            const int n = nt * 16 + p;
            floatx4 acc = {0.f, 0.f, 0.f, 0.f};
            acc = __builtin_amdgcn_mfma_f32_16x16x32_bf16(ax, w1f[nt], acc, 0, 0, 0);
            const float bn = sb1[n];
            #pragma unroll
            for (int r = 0; r < 4; ++r) {
                const float h1 = fast_tanh(acc[r] + bn);
                a1c[nt * 4 + r] = __builtin_fmaf(-h1, h1, 1.0f);
                T[(q * 4 + r) * PITCH_H + lt * 16 + p] = (__bf16)h1;
            }
        }
        // wave-private LDS, in-order DS ops: no barrier needed (RAW/WAR safe)
        ah[half * 2 + 0] = *(const bf16x8*)&T[p * PITCH_H + q * 8];
        ah[half * 2 + 1] = *(const bf16x8*)&T[p * PITCH_H + 32 + q * 8];
    }
}

__device__ __forceinline__ void phase1_h2(
        const bf16x8* ah, const bf16x8* W2sv, const float* sb2,
        __bf16* T, int p, int q, bf16x8* ah2, bf16x8* aa) {
    #pragma unroll
    for (int half = 0; half < 2; ++half) {
        #pragma unroll
        for (int lt = 0; lt < 4; ++lt) {
            const int nt = half * 4 + lt;
            const int n = nt * 16 + p;
            floatx4 acc = {0.f, 0.f, 0.f, 0.f};
            #pragma unroll
            for (int kb = 0; kb < 4; ++kb)
                acc = __builtin_amdgcn_mfma_f32_16x16x32_bf16(
                        ah[kb], W2sv[(kb * 128 + n) * 4 + q], acc, 0, 0, 0);
            const float bn = sb2[n];
            #pragma unroll
            for (int r = 0; r < 4; ++r) {
                const float h2 = fast_tanh(acc[r] + bn);
                T[(q * 4 + r) * PITCH_H + lt * 16 + p] = (__bf16)h2;
            }
        }
        ah2[half * 2 + 0] = *(const bf16x8*)&T[p * PITCH_H + q * 8];
        ah2[half * 2 + 1] = *(const bf16x8*)&T[p * PITCH_H + 32 + q * 8];
    }
    // a2 A-frags in-register: a2 = 1 - h2^2 (elementwise in k)
    #pragma unroll
    for (int kb = 0; kb < 4; ++kb) {
        #pragma unroll
        for (int j = 0; j < 8; ++j) {
            const float f = (float)ah2[kb][j];
            aa[kb][j] = (__bf16)__builtin_fmaf(-f, f, 1.0f);
        }
    }
}

__device__ __forceinline__ void phase3_dz(
        const bf16x8* ah2, const bf16x8* w3f, float b3v,
        int s0, int p, int q, float* out) {
    floatx4 acc3 = {0.f, 0.f, 0.f, 0.f};
    #pragma unroll
    for (int kb = 0; kb < 4; ++kb)
        acc3 = __builtin_amdgcn_mfma_f32_16x16x32_bf16(ah2[kb], w3f[kb], acc3, 0, 0, 0);
    if (p < 8) {
        #pragma unroll
        for (int r = 0; r < 4; ++r)
            out[(size_t)(s0 + q * 4 + r) * 8 + p] = acc3[r] + b3v;
    }
}

__device__ __forceinline__ void phase2_tr(
        const bf16x8* aa, const float* a1c, const bf16x8* GTsv,
        int s0, int p, int q, float* out) {
    float tr[4] = {0.f, 0.f, 0.f, 0.f};
    #pragma unroll
    for (int nt = 0; nt < 8; ++nt) {
        const int n = nt * 16 + p;
        floatx4 acc = {0.f, 0.f, 0.f, 0.f};
        #pragma unroll
        for (int kb = 0; kb < 4; ++kb)
            acc = __builtin_amdgcn_mfma_f32_16x16x32_bf16(
                    aa[kb], GTsv[(kb * 128 + n) * 4 + q], acc, 0, 0, 0);
        #pragma unroll
        for (int r = 0; r < 4; ++r)
            tr[r] = __builtin_fmaf(a1c[nt * 4 + r], acc[r], tr[r]);
    }
    #pragma unroll
    for (int r = 0; r < 4; ++r) {
        float v = tr[r];
        v += __shfl_xor(v, 1, 64);
        v += __shfl_xor(v, 2, 64);
        v += __shfl_xor(v, 4, 64);
        v += __shfl_xor(v, 8, 64);
        tr[r] = v;
    }
    if (p == 0) {
        #pragma unroll
        for (int r = 0; r < 4; ++r)
            out[(size_t)BATCH * 8 + s0 + q * 4 + r] = -tr[r];
    }
}

// Structure rationale (rounds 0-8 evidence):
//  - R8 (GT+W2 in LDS, W1/W3 reg-hoisted, half-tile transpose): best, cnf
//    ~36us. R7 counters: no pipe near ceiling, 12 waves/CU == 8 waves/CU ->
//    latency-bound; occupancy capped by LDS 74 KB anyway.
//  - NEW: two-group interleave. Each wave runs TWO independent 16-sample
//    groups, phase-staggered (P0a P0b P1a P3a P1b P2a P3b P2b) -> each
//    group's stalls (exp latency, LDS-RT lgkm waits, MFMA latency) overlap
//    the other group's independent work. Shared half-tile T stays correct:
//    DS ops are wave-private + in-order; each round-trip is write->read
//    self-contained in source order.
//  - z loads (both groups) + W1/W3 frag loads hoisted ABOVE the staging
//    loop: HBM/L2 latency hides under the 64 KB LDS staging + barrier.
//  - launch_bounds(256,2) ONLY: budget-256 is the proven spill-free regime
//    (R0 128, R3 72, R7 128 VGPR). min-waves>=4 attrs -> 64-VGPR acc-split
//    + ~200 MB scratch (R1/R2). Watch: VGPR must land <256, FETCH ~5 MB.
__global__ __launch_bounds__(256, 2) void cnf_main(
        const float* __restrict__ z, const float* __restrict__ t_ptr,
        const float* __restrict__ b1g, const float* __restrict__ b2g,
        const float* __restrict__ b3g, const __bf16* __restrict__ ws,
        float* __restrict__ out) {
    __shared__ __bf16 sW2s[16384];            // 32 KB
    __shared__ __bf16 sGTs[16384];            // 32 KB
    __shared__ float sb1[128];
    __shared__ float sb2[128];
    __shared__ __bf16 tile[4][16 * PITCH_H];  // per-wave half-width scratch

    const int tid = threadIdx.x;
    const int lane = tid & 63;
    const int w = tid >> 6;
    const int p = lane & 15;       // C/D col, A row (sample), B col
    const int q = lane >> 4;       // quad
    const int sbase = blockIdx.x * 128 + w * 32;
    const float tval = t_ptr[0];

    // ---- hoisted loads: z for BOTH groups + W1/W3 frags (latency hides
    // under the staging copy + barrier below) ----
    bf16x8 ax0, ax1;
    #pragma unroll
    for (int j = 0; j < 8; ++j) { ax0[j] = (__bf16)0.0f; ax1[j] = (__bf16)0.0f; }
    if (q == 0) {
        const float4* zp0 = (const float4*)(z + (size_t)(sbase + p) * 8);
        const float4* zp1 = (const float4*)(z + (size_t)(sbase + 16 + p) * 8);
        const float4 a0 = zp0[0], a1 = zp0[1], c0 = zp1[0], c1 = zp1[1];
        ax0[0] = (__bf16)a0.x; ax0[1] = (__bf16)a0.y;
        ax0[2] = (__bf16)a0.z; ax0[3] = (__bf16)a0.w;
        ax0[4] = (__bf16)a1.x; ax0[5] = (__bf16)a1.y;
        ax0[6] = (__bf16)a1.z; ax0[7] = (__bf16)a1.w;
        ax1[0] = (__bf16)c0.x; ax1[1] = (__bf16)c0.y;
        ax1[2] = (__bf16)c0.z; ax1[3] = (__bf16)c0.w;
        ax1[4] = (__bf16)c1.x; ax1[5] = (__bf16)c1.y;
        ax1[6] = (__bf16)c1.z; ax1[7] = (__bf16)c1.w;
    } else if (q == 1) {
        ax0[0] = (__bf16)tval;   // x[8] = t
        ax1[0] = (__bf16)tval;
    }

    const bf16x8* W1g = (const bf16x8*)(ws + 32768);
    const bf16x8* W3g = (const bf16x8*)(ws + 36864);
    bf16x8 w1f[8];
    #pragma unroll
    for (int nt = 0; nt < 8; ++nt) w1f[nt] = W1g[(nt * 16 + p) * 4 + q];
    bf16x8 w3f[4];
    #pragma unroll
    for (int kb = 0; kb < 4; ++kb) w3f[kb] = W3g[(kb * 16 + p) * 4 + q];

    // ---- stage W2 + GT + biases into LDS ----
    {
        uint4* dst = (uint4*)sW2s;
        const uint4* src = (const uint4*)ws;
        #pragma unroll
        for (int i = 0; i < 8; ++i) dst[tid + i * 256] = src[tid + i * 256];
        uint4* dstg = (uint4*)sGTs;
        const uint4* srcg = (const uint4*)(ws + 16384);
        #pragma unroll
        for (int i = 0; i < 8; ++i) dstg[tid + i * 256] = srcg[tid + i * 256];
        if (tid < 128) { sb1[tid] = b1g[tid]; sb2[tid] = b2g[tid]; }
    }
    __syncthreads();

    __bf16* T = tile[w];
    const bf16x8* W2sv = (const bf16x8*)sW2s;
    const bf16x8* GTsv = (const bf16x8*)sGTs;
    const float b3v = (p < 8) ? b3g[p] : 0.0f;
    const int s0a = sbase;
    const int s0b = sbase + 16;

    // ---- staggered two-group schedule ----
    float a1c0[32], a1c1[32];
    bf16x8 ah0[4], ah1[4];
    phase0_h1(ax0, w1f, sb1, T, p, q, a1c0, ah0);       // P0(g0)
    phase0_h1(ax1, w1f, sb1, T, p, q, a1c1, ah1);       // P0(g1)

    bf16x8 ah2_0[4], aa0[4];
    phase1_h2(ah0, W2sv, sb2, T, p, q, ah2_0, aa0);     // P1(g0)
    phase3_dz(ah2_0, w3f, b3v, s0a, p, q, out);         // P3(g0)

    bf16x8 ah2_1[4], aa1[4];
    phase1_h2(ah1, W2sv, sb2, T, p, q, ah2_1, aa1);     // P1(g1)
    phase2_tr(aa0, a1c0, GTsv, s0a, p, q, out);         // P2(g0)

    phase3_dz(ah2_1, w3f, b3v, s0b, p, q, out);         // P3(g1)
    phase2_tr(aa1, a1c1, GTsv, s0b, p, q, out);         // P2(g1)
}

extern "C" void kernel_launch(void* const* d_in, const int* in_sizes, int n_in,
                              void* d_out, int out_size, void* d_ws, size_t ws_size,
                              hipStream_t stream) {
    const float* z  = (const float*)d_in[0];
    // d_in[1] = logp_z (unused by the reference math)
    const float* t  = (const float*)d_in[2];
    const float* W1 = (const float*)d_in[3];
    const float* b1 = (const float*)d_in[4];
    const float* W2 = (const float*)d_in[5];
    const float* b2 = (const float*)d_in[6];
    const float* W3 = (const float*)d_in[7];
    const float* b3 = (const float*)d_in[8];
    __bf16* ws = (__bf16*)d_ws;
    float* out = (float*)d_out;

    prep_kernel<<<88, 256, 0, stream>>>(W1, W2, W3, ws);
    cnf_main<<<1024, 256, 0, stream>>>(z, t, b1, b2, b3, ws, out);
}

// Round 10
// 94.352 us; speedup vs baseline: 1.0314x; 1.0314x over previous
//
#include <hip/hip_runtime.h>
#include <hip/hip_bf16.h>

#define BATCH 131072
#define PITCH_Q 40   // quarter-tile row: 32 + 8 pad bf16 (80 B = 5x16B, rows 16B-aligned)

typedef __bf16 bf16x8 __attribute__((ext_vector_type(8)));
typedef float floatx4 __attribute__((ext_vector_type(4)));

__device__ __forceinline__ float fast_tanh(float x) {
    // tanh(x) = 1 - 2/(exp(2x)+1); exp overflow -> inf -> rcp -> 0 -> +1 (correct limit)
    float e = __expf(2.0f * x);
    return 1.0f - 2.0f * __builtin_amdgcn_rcpf(e + 1.0f);
}

// d_ws element layout (bf16):
// [0,16384)       W2s : B-frag swizzled W2              (GEMM1: h2pre = h1 @ W2)
// [16384,32768)   GTs : B-frag swizzled G^T, G=W2*C^T   (GEMM2: U = a2 @ G^T)
// [32768,36864)   W1s : B-frag swizzled W1, K pad to 32 (GEMM0: h1pre = [z|t] @ W1)
// [36864,38912)   W3s : B-frag swizzled W3, N pad to 16 (GEMM3: dz = h2 @ W3)
// swizzle: idx = ((kb*N + n)*4 + q)*8 + j  <->  B[k = kb*32 + q*8 + j][n]

__global__ void prep_kernel(const float* __restrict__ W1,
                            const float* __restrict__ W2,
                            const float* __restrict__ W3,
                            __bf16* __restrict__ ws) {
    int idx = blockIdx.x * 256 + threadIdx.x;
    if (idx < 16384) {
        int j = idx & 7, q = (idx >> 3) & 3, n = (idx >> 5) & 127, kb = idx >> 12;
        int k = kb * 32 + q * 8 + j;
        ws[idx] = (__bf16)W2[k * 128 + n];
        float c = 0.0f;
        #pragma unroll
        for (int d = 0; d < 8; ++d) c += W3[k * 8 + d] * W1[d * 128 + n];
        ws[16384 + idx] = (__bf16)(W2[n * 128 + k] * c);
    } else if (idx < 20480) {
        int t = idx - 16384;
        int j = t & 7, q = (t >> 3) & 3, n = t >> 5;   // kb==0 only
        int k = q * 8 + j;
        ws[32768 + t] = (k < 9) ? (__bf16)W1[k * 128 + n] : (__bf16)0.0f;
    } else if (idx < 22528) {
        int t = idx - 20480;
        int j = t & 7, q = (t >> 3) & 3, n = (t >> 5) & 15, kb = t >> 9;
        int k = kb * 32 + q * 8 + j;
        ws[36864 + t] = (n < 8) ? (__bf16)W3[k * 8 + n] : (__bf16)0.0f;
    }
}

// Structure rationale (rounds 0-9 evidence):
//  - R9 (two-group stagger, same LDS traffic): NEUTRAL -> dependency depth
//    is not the limiter; the per-CU LDS pipe is (64 KB of B-frag reads per
//    16 samples; ~7us/CU floor). R7: more waves/CU didn't help (same pipe).
//  - THIS ROUND: share each W2/GT B-frag LDS read across BOTH groups' MFMAs
//    (fused loops) -> B-frag reads halved (128 -> 64 per 32 samples).
//  - Biases hoisted to regs (b1f/b2f): 64 fewer LDS reads/iter, sb1/sb2 gone.
//  - Quarter-width tiles, one per group per wave (2x1280 B/wave): groups'
//    transposes don't serialize on one tile. LDS = 32+32+10+0 = 74 KB ->
//    2 blocks/CU, 8 waves/CU (same residency as R8/R9).
//  - GEMM0 BEFORE the barrier (touches only regs + private tile): overlaps
//    the staging drain.
//  - launch_bounds(256,2) ONLY: budget-256 is the proven spill-free regime
//    (R0 128, R3 72, R7 128 VGPR). min-waves>=4 attrs -> 64-VGPR acc-split
//    + ~200 MB scratch spill (R1/R2). Watch: FETCH must stay ~5 MB.
__global__ __launch_bounds__(256, 2) void cnf_main(
        const float* __restrict__ z, const float* __restrict__ t_ptr,
        const float* __restrict__ b1g, const float* __restrict__ b2g,
        const float* __restrict__ b3g, const __bf16* __restrict__ ws,
        float* __restrict__ out) {
    __shared__ __bf16 sW2s[16384];                         // 32 KB
    __shared__ __bf16 sGTs[16384];                         // 32 KB
    __shared__ __align__(16) __bf16 tile[4][2][16 * PITCH_Q];  // 10 KB

    const int tid = threadIdx.x;
    const int lane = tid & 63;
    const int w = tid >> 6;
    const int p = lane & 15;       // C/D col, A row (sample), B col
    const int q = lane >> 4;       // quad
    const int sbase = blockIdx.x * 128 + w * 32;
    const float tval = t_ptr[0];

    // ---- hoisted loads (latency hides under staging + GEMM0) ----
    bf16x8 ax0, ax1;
    #pragma unroll
    for (int j = 0; j < 8; ++j) { ax0[j] = (__bf16)0.0f; ax1[j] = (__bf16)0.0f; }
    if (q == 0) {
        const float4* zp0 = (const float4*)(z + (size_t)(sbase + p) * 8);
        const float4* zp1 = (const float4*)(z + (size_t)(sbase + 16 + p) * 8);
        const float4 a0 = zp0[0], a1 = zp0[1], c0 = zp1[0], c1 = zp1[1];
        ax0[0] = (__bf16)a0.x; ax0[1] = (__bf16)a0.y;
        ax0[2] = (__bf16)a0.z; ax0[3] = (__bf16)a0.w;
        ax0[4] = (__bf16)a1.x; ax0[5] = (__bf16)a1.y;
        ax0[6] = (__bf16)a1.z; ax0[7] = (__bf16)a1.w;
        ax1[0] = (__bf16)c0.x; ax1[1] = (__bf16)c0.y;
        ax1[2] = (__bf16)c0.z; ax1[3] = (__bf16)c0.w;
        ax1[4] = (__bf16)c1.x; ax1[5] = (__bf16)c1.y;
        ax1[6] = (__bf16)c1.z; ax1[7] = (__bf16)c1.w;
    } else if (q == 1) {
        ax0[0] = (__bf16)tval;   // x[8] = t
        ax1[0] = (__bf16)tval;
    }

    const bf16x8* W1g = (const bf16x8*)(ws + 32768);
    const bf16x8* W3g = (const bf16x8*)(ws + 36864);
    bf16x8 w1f[8];
    #pragma unroll
    for (int nt = 0; nt < 8; ++nt) w1f[nt] = W1g[(nt * 16 + p) * 4 + q];
    bf16x8 w3f[4];
    #pragma unroll
    for (int kb = 0; kb < 4; ++kb) w3f[kb] = W3g[(kb * 16 + p) * 4 + q];
    float b1f[8], b2f[8];
    #pragma unroll
    for (int nt = 0; nt < 8; ++nt) { b1f[nt] = b1g[nt * 16 + p]; b2f[nt] = b2g[nt * 16 + p]; }
    const float b3v = (p < 8) ? b3g[p] : 0.0f;

    // ---- stage W2 + GT into LDS ----
    {
        uint4* dst = (uint4*)sW2s;
        const uint4* src = (const uint4*)ws;
        #pragma unroll
        for (int i = 0; i < 8; ++i) dst[tid + i * 256] = src[tid + i * 256];
        uint4* dstg = (uint4*)sGTs;
        const uint4* srcg = (const uint4*)(ws + 16384);
        #pragma unroll
        for (int i = 0; i < 8; ++i) dstg[tid + i * 256] = srcg[tid + i * 256];
    }

    __bf16* Ta = tile[w][0];
    __bf16* Tb = tile[w][1];

    // ---- GEMM0 (pre-barrier: registers + private tile only) ----
    float a1c0[32], a1c1[32];
    bf16x8 ah0[4], ah1[4];
    #pragma unroll
    for (int c = 0; c < 4; ++c) {
        floatx4 aA[2], aB[2];
        #pragma unroll
        for (int lt = 0; lt < 2; ++lt) {
            floatx4 zz = {0.f, 0.f, 0.f, 0.f};
            aA[lt] = __builtin_amdgcn_mfma_f32_16x16x32_bf16(ax0, w1f[2 * c + lt], zz, 0, 0, 0);
            aB[lt] = __builtin_amdgcn_mfma_f32_16x16x32_bf16(ax1, w1f[2 * c + lt], zz, 0, 0, 0);
        }
        #pragma unroll
        for (int lt = 0; lt < 2; ++lt) {
            const int nt = 2 * c + lt;
            const float bn = b1f[nt];
            #pragma unroll
            for (int r = 0; r < 4; ++r) {
                const float h1a = fast_tanh(aA[lt][r] + bn);
                a1c0[nt * 4 + r] = __builtin_fmaf(-h1a, h1a, 1.0f);
                Ta[(q * 4 + r) * PITCH_Q + lt * 16 + p] = (__bf16)h1a;
                const float h1b = fast_tanh(aB[lt][r] + bn);
                a1c1[nt * 4 + r] = __builtin_fmaf(-h1b, h1b, 1.0f);
                Tb[(q * 4 + r) * PITCH_Q + lt * 16 + p] = (__bf16)h1b;
            }
        }
        // wave-private in-order DS: write->read round-trip safe, no barrier
        ah0[c] = *(const bf16x8*)&Ta[p * PITCH_Q + q * 8];
        ah1[c] = *(const bf16x8*)&Tb[p * PITCH_Q + q * 8];
    }

    __syncthreads();
    const bf16x8* W2sv = (const bf16x8*)sW2s;
    const bf16x8* GTsv = (const bf16x8*)sGTs;

    // ---- GEMM1: fused two-group, each W2 B-frag read feeds 2 MFMAs ----
    bf16x8 ah2_0[4], ah2_1[4];
    #pragma unroll
    for (int c = 0; c < 4; ++c) {
        floatx4 aA[2] = {{0.f, 0.f, 0.f, 0.f}, {0.f, 0.f, 0.f, 0.f}};
        floatx4 aB[2] = {{0.f, 0.f, 0.f, 0.f}, {0.f, 0.f, 0.f, 0.f}};
        #pragma unroll
        for (int kb = 0; kb < 4; ++kb) {
            #pragma unroll
            for (int lt = 0; lt < 2; ++lt) {
                const int n = (2 * c + lt) * 16 + p;
                const bf16x8 wf = W2sv[(kb * 128 + n) * 4 + q];
                aA[lt] = __builtin_amdgcn_mfma_f32_16x16x32_bf16(ah0[kb], wf, aA[lt], 0, 0, 0);
                aB[lt] = __builtin_amdgcn_mfma_f32_16x16x32_bf16(ah1[kb], wf, aB[lt], 0, 0, 0);
            }
        }
        #pragma unroll
        for (int lt = 0; lt < 2; ++lt) {
            const int nt = 2 * c + lt;
            const float bn = b2f[nt];
            #pragma unroll
            for (int r = 0; r < 4; ++r) {
                const float h2a = fast_tanh(aA[lt][r] + bn);
                Ta[(q * 4 + r) * PITCH_Q + lt * 16 + p] = (__bf16)h2a;
                const float h2b = fast_tanh(aB[lt][r] + bn);
                Tb[(q * 4 + r) * PITCH_Q + lt * 16 + p] = (__bf16)h2b;
            }
        }
        ah2_0[c] = *(const bf16x8*)&Ta[p * PITCH_Q + q * 8];
        ah2_1[c] = *(const bf16x8*)&Tb[p * PITCH_Q + q * 8];
    }

    // ---- GEMM3: dz = h2 @ W3 (reg B-frags), both groups ----
    floatx4 d3A = {0.f, 0.f, 0.f, 0.f}, d3B = {0.f, 0.f, 0.f, 0.f};
    #pragma unroll
    for (int kb = 0; kb < 4; ++kb) {
        d3A = __builtin_amdgcn_mfma_f32_16x16x32_bf16(ah2_0[kb], w3f[kb], d3A, 0, 0, 0);
        d3B = __builtin_amdgcn_mfma_f32_16x16x32_bf16(ah2_1[kb], w3f[kb], d3B, 0, 0, 0);
    }
    if (p < 8) {
        #pragma unroll
        for (int r = 0; r < 4; ++r) {
            out[(size_t)(sbase + q * 4 + r) * 8 + p] = d3A[r] + b3v;
            out[(size_t)(sbase + 16 + q * 4 + r) * 8 + p] = d3B[r] + b3v;
        }
    }

    // a2 A-frags in-register AFTER GEMM3 (ah2 dies here; trims peak VGPR)
    bf16x8 aa0[4], aa1[4];
    #pragma unroll
    for (int kb = 0; kb < 4; ++kb) {
        #pragma unroll
        for (int j = 0; j < 8; ++j) {
            const float fa = (float)ah2_0[kb][j];
            aa0[kb][j] = (__bf16)__builtin_fmaf(-fa, fa, 1.0f);
            const float fb = (float)ah2_1[kb][j];
            aa1[kb][j] = (__bf16)__builtin_fmaf(-fb, fb, 1.0f);
        }
    }

    // ---- GEMM2: fused two-group, each GT B-frag read feeds 2 MFMAs ----
    float trA[4] = {0.f, 0.f, 0.f, 0.f}, trB[4] = {0.f, 0.f, 0.f, 0.f};
    #pragma unroll
    for (int nt = 0; nt < 8; ++nt) {
        const int n = nt * 16 + p;
        floatx4 uA = {0.f, 0.f, 0.f, 0.f}, uB = {0.f, 0.f, 0.f, 0.f};
        #pragma unroll
        for (int kb = 0; kb < 4; ++kb) {
            const bf16x8 gf = GTsv[(kb * 128 + n) * 4 + q];
            uA = __builtin_amdgcn_mfma_f32_16x16x32_bf16(aa0[kb], gf, uA, 0, 0, 0);
            uB = __builtin_amdgcn_mfma_f32_16x16x32_bf16(aa1[kb], gf, uB, 0, 0, 0);
        }
        #pragma unroll
        for (int r = 0; r < 4; ++r) {
            trA[r] = __builtin_fmaf(a1c0[nt * 4 + r], uA[r], trA[r]);
            trB[r] = __builtin_fmaf(a1c1[nt * 4 + r], uB[r], trB[r]);
        }
    }

    // ---- reduce traces over the 16 lanes of each quad; write -trace ----
    #pragma unroll
    for (int r = 0; r < 4; ++r) {
        float va = trA[r];
        va += __shfl_xor(va, 1, 64);
        va += __shfl_xor(va, 2, 64);
        va += __shfl_xor(va, 4, 64);
        va += __shfl_xor(va, 8, 64);
        trA[r] = va;
        float vb = trB[r];
        vb += __shfl_xor(vb, 1, 64);
        vb += __shfl_xor(vb, 2, 64);
        vb += __shfl_xor(vb, 4, 64);
        vb += __shfl_xor(vb, 8, 64);
        trB[r] = vb;
    }
    if (p == 0) {
        #pragma unroll
        for (int r = 0; r < 4; ++r) {
            out[(size_t)BATCH * 8 + sbase + q * 4 + r] = -trA[r];
            out[(size_t)BATCH * 8 + sbase + 16 + q * 4 + r] = -trB[r];
        }
    }
}

extern "C" void kernel_launch(void* const* d_in, const int* in_sizes, int n_in,
                              void* d_out, int out_size, void* d_ws, size_t ws_size,
                              hipStream_t stream) {
    const float* z  = (const float*)d_in[0];
    // d_in[1] = logp_z (unused by the reference math)
    const float* t  = (const float*)d_in[2];
    const float* W1 = (const float*)d_in[3];
    const float* b1 = (const float*)d_in[4];
    const float* W2 = (const float*)d_in[5];
    const float* b2 = (const float*)d_in[6];
    const float* W3 = (const float*)d_in[7];
    const float* b3 = (const float*)d_in[8];
    __bf16* ws = (__bf16*)d_ws;
    float* out = (float*)d_out;

    prep_kernel<<<88, 256, 0, stream>>>(W1, W2, W3, ws);
    cnf_main<<<1024, 256, 0, stream>>>(z, t, b1, b2, b3, ws, out);
}

// Round 11
// 89.951 us; speedup vs baseline: 1.0819x; 1.0489x over previous
//
#include <hip/hip_runtime.h>
#include <hip/hip_bf16.h>

#define BATCH 131072
#define PITCH_H 72   // half-tile row: 64 + 8 pad bf16 (144 B = 9x16B; rows stay 16B-aligned)

typedef __bf16 bf16x4 __attribute__((ext_vector_type(4)));
typedef __bf16 bf16x8 __attribute__((ext_vector_type(8)));
typedef float floatx4 __attribute__((ext_vector_type(4)));

__device__ __forceinline__ float fast_tanh(float x) {
    // tanh(x) = 1 - 2/(exp(2x)+1); exp overflow -> inf -> rcp -> 0 -> +1 (correct limit)
    float e = __expf(2.0f * x);
    return 1.0f - 2.0f * __builtin_amdgcn_rcpf(e + 1.0f);
}

// d_ws element layout (bf16):
// [0,16384)       W2s : frag-swizzled W2                (GEMM1)
// [16384,32768)   GTs : frag-swizzled G^T, G=W2*C^T     (GEMM2)
// [32768,36864)   W1s : frag-swizzled W1, K pad to 32; rows k=9,10 carry b1 hi/lo (GEMM0)
// [36864,38912)   W3s : frag-swizzled W3, N pad to 16   (GEMM3)
// swizzle: idx = ((kb*N + n)*4 + q)*8 + j  <->  M[k = kb*32 + q*8 + j][n]
// NOTE (operand-swap symmetry): the A-frag of M^T and the B-frag of M have
// IDENTICAL per-lane data for mfma_16x16x32, so these same fragments serve
// the transposed GEMMs below with no prep change.

__global__ void prep_kernel(const float* __restrict__ W1,
                            const float* __restrict__ W2,
                            const float* __restrict__ W3,
                            const float* __restrict__ b1,
                            __bf16* __restrict__ ws) {
    int idx = blockIdx.x * 256 + threadIdx.x;
    if (idx < 16384) {
        int j = idx & 7, q = (idx >> 3) & 3, n = (idx >> 5) & 127, kb = idx >> 12;
        int k = kb * 32 + q * 8 + j;
        ws[idx] = (__bf16)W2[k * 128 + n];
        float c = 0.0f;
        #pragma unroll
        for (int d = 0; d < 8; ++d) c += W3[k * 8 + d] * W1[d * 128 + n];
        ws[16384 + idx] = (__bf16)(W2[n * 128 + k] * c);
    } else if (idx < 20480) {
        int t = idx - 16384;
        int j = t & 7, q = (t >> 3) & 3, n = t >> 5;   // kb==0 only
        int k = q * 8 + j;
        __bf16 v = (__bf16)0.0f;
        if (k < 9) v = (__bf16)W1[k * 128 + n];
        else if (k == 9) v = (__bf16)b1[n];                    // bias hi (x[9]=1)
        else if (k == 10) {                                    // bias lo (x[10]=1)
            float hi = (float)(__bf16)b1[n];
            v = (__bf16)(b1[n] - hi);
        }
        ws[32768 + t] = v;
    } else if (idx < 22528) {
        int t = idx - 20480;
        int j = t & 7, q = (t >> 3) & 3, n = (t >> 5) & 15, kb = t >> 9;
        int k = kb * 32 + q * 8 + j;
        ws[36864 + t] = (n < 8) ? (__bf16)W3[k * 8 + n] : (__bf16)0.0f;
    }
}

// Structure rationale (rounds 0-10 evidence):
//  - R7/R9/R10: occupancy-null, stagger-null, LDS-share +2us -> VALU-bound
//    (real VALUBusy ~55%): tanh chains + 128 scalar cvt + 128 scattered
//    ds_write_b16 + bias adds + 16 trace shuffles per wave-iter.
//  - THIS ROUND: every GEMM computed TRANSPOSED via operand swap
//    (mfma(Wfrag, Xfrag) -> D=[hidden][sample]); frag data identical, prep
//    swizzles unchanged. Wins: tile writes contiguous (bf16x4 b64, 4x fewer
//    DS writes, pk-cvts), b1 folded into GEMM0 K-slots (hi/lo split, f32-
//    accurate), b2/b3 folded into the MFMA C-operand (f32-exact), trace =
//    1 scalar/lane + 2 shuffles (was 4x4 + 16), dz = 1 float4 store/lane.
//  - One shared half-tile per wave (groups serial; wave-private in-order
//    DS). LDS = 32(W2)+32(GT)+9(tiles)+0.5(b2) = 73.5 KB -> 2 blocks/CU.
//  - launch_bounds(256,2) ONLY: budget-256 is the proven spill-free regime
//    (R0 128, R3 72, R7 128 VGPR). min-waves>=4 attrs -> 64-VGPR acc-split
//    + ~200 MB scratch spill (R1/R2). Watch: FETCH must stay ~5 MB.
__global__ __launch_bounds__(256, 2) void cnf_main(
        const float* __restrict__ z, const float* __restrict__ t_ptr,
        const float* __restrict__ b1g, const float* __restrict__ b2g,
        const float* __restrict__ b3g, const __bf16* __restrict__ ws,
        float* __restrict__ out) {
    __shared__ __bf16 sW2s[16384];                             // 32 KB
    __shared__ __bf16 sGTs[16384];                             // 32 KB
    __shared__ float sb2f[128];                                // 512 B
    __shared__ __align__(16) __bf16 tile[4][16 * PITCH_H];     // 9 KB

    const int tid = threadIdx.x;
    const int lane = tid & 63;
    const int w = tid >> 6;
    const int p = lane & 15;       // sample index (C/D col in all GEMMs)
    const int q = lane >> 4;       // quad (C/D row group)
    const int sbase = blockIdx.x * 128 + w * 32;
    const float tval = t_ptr[0];

    // ---- hoisted loads (latency hides under staging + GEMM0) ----
    bf16x8 ax0, ax1;   // B-frag of X^T: lane holds x[sample p][k=q*8+j]
    #pragma unroll
    for (int j = 0; j < 8; ++j) { ax0[j] = (__bf16)0.0f; ax1[j] = (__bf16)0.0f; }
    if (q == 0) {
        const float4* zp0 = (const float4*)(z + (size_t)(sbase + p) * 8);
        const float4* zp1 = (const float4*)(z + (size_t)(sbase + 16 + p) * 8);
        const float4 a0 = zp0[0], a1 = zp0[1], c0 = zp1[0], c1 = zp1[1];
        ax0[0] = (__bf16)a0.x; ax0[1] = (__bf16)a0.y;
        ax0[2] = (__bf16)a0.z; ax0[3] = (__bf16)a0.w;
        ax0[4] = (__bf16)a1.x; ax0[5] = (__bf16)a1.y;
        ax0[6] = (__bf16)a1.z; ax0[7] = (__bf16)a1.w;
        ax1[0] = (__bf16)c0.x; ax1[1] = (__bf16)c0.y;
        ax1[2] = (__bf16)c0.z; ax1[3] = (__bf16)c0.w;
        ax1[4] = (__bf16)c1.x; ax1[5] = (__bf16)c1.y;
        ax1[6] = (__bf16)c1.z; ax1[7] = (__bf16)c1.w;
    } else if (q == 1) {
        ax0[0] = (__bf16)tval; ax0[1] = (__bf16)1.0f; ax0[2] = (__bf16)1.0f; // k=8:t, 9/10: bias ones
        ax1[0] = (__bf16)tval; ax1[1] = (__bf16)1.0f; ax1[2] = (__bf16)1.0f;
    }

    const bf16x8* W1g = (const bf16x8*)(ws + 32768);
    const bf16x8* W3g = (const bf16x8*)(ws + 36864);
    bf16x8 w1f[8];
    #pragma unroll
    for (int nt = 0; nt < 8; ++nt) w1f[nt] = W1g[(nt * 16 + p) * 4 + q];
    bf16x8 w3f[4];
    #pragma unroll
    for (int kb = 0; kb < 4; ++kb) w3f[kb] = W3g[(kb * 16 + p) * 4 + q];
    floatx4 b3f = {0.f, 0.f, 0.f, 0.f};
    if (q < 2) b3f = *(const floatx4*)(b3g + q * 4);   // dz rows q*4+r (real d<8)

    // ---- stage W2 + GT + b2 into LDS ----
    {
        uint4* dst = (uint4*)sW2s;
        const uint4* src = (const uint4*)ws;
        #pragma unroll
        for (int i = 0; i < 8; ++i) dst[tid + i * 256] = src[tid + i * 256];
        uint4* dstg = (uint4*)sGTs;
        const uint4* srcg = (const uint4*)(ws + 16384);
        #pragma unroll
        for (int i = 0; i < 8; ++i) dstg[tid + i * 256] = srcg[tid + i * 256];
        if (tid < 128) sb2f[tid] = b2g[tid];
    }

    __bf16* T = tile[w];

    // ---- GEMM0 (pre-barrier): h1^T = mfma(W1^T-frag, X^T-frag); bias via K-slots ----
    // lane holds h1[sample p][hidden nt*16+q*4+r]
    float a1c0[32], a1c1[32];
    bf16x8 aha[4], ahb[4];
    #pragma unroll
    for (int h = 0; h < 2; ++h) {
        floatx4 accA[4], accB[4];
        #pragma unroll
        for (int lt = 0; lt < 4; ++lt) {
            const floatx4 zz = {0.f, 0.f, 0.f, 0.f};
            accA[lt] = __builtin_amdgcn_mfma_f32_16x16x32_bf16(w1f[4 * h + lt], ax0, zz, 0, 0, 0);
            accB[lt] = __builtin_amdgcn_mfma_f32_16x16x32_bf16(w1f[4 * h + lt], ax1, zz, 0, 0, 0);
        }
        #pragma unroll
        for (int lt = 0; lt < 4; ++lt) {            // group a epilogue
            bf16x4 v;
            #pragma unroll
            for (int r = 0; r < 4; ++r) {
                const float h1 = fast_tanh(accA[lt][r]);
                a1c0[(4 * h + lt) * 4 + r] = __builtin_fmaf(-h1, h1, 1.0f);
                v[r] = (__bf16)h1;
            }
            *(bf16x4*)&T[p * PITCH_H + lt * 16 + q * 4] = v;   // contiguous b64
        }
        // wave-private in-order DS: write->read round-trip safe, no barrier
        aha[2 * h]     = *(const bf16x8*)&T[p * PITCH_H + q * 8];
        aha[2 * h + 1] = *(const bf16x8*)&T[p * PITCH_H + 32 + q * 8];
        #pragma unroll
        for (int lt = 0; lt < 4; ++lt) {            // group b epilogue (tile reused)
            bf16x4 v;
            #pragma unroll
            for (int r = 0; r < 4; ++r) {
                const float h1 = fast_tanh(accB[lt][r]);
                a1c1[(4 * h + lt) * 4 + r] = __builtin_fmaf(-h1, h1, 1.0f);
                v[r] = (__bf16)h1;
            }
            *(bf16x4*)&T[p * PITCH_H + lt * 16 + q * 4] = v;
        }
        ahb[2 * h]     = *(const bf16x8*)&T[p * PITCH_H + q * 8];
        ahb[2 * h + 1] = *(const bf16x8*)&T[p * PITCH_H + 32 + q * 8];
    }

    __syncthreads();
    const bf16x8* W2sv = (const bf16x8*)sW2s;
    const bf16x8* GTsv = (const bf16x8*)sGTs;

    // ---- GEMM1: h2^T = mfma(W2^T-frag, h1^T-frag, C=b2); shared W2 reads ----
    bf16x8 ah2a[4], ah2b[4];
    #pragma unroll
    for (int h = 0; h < 2; ++h) {
        floatx4 accA[4], accB[4];
        #pragma unroll
        for (int lt = 0; lt < 4; ++lt) {
            const int nt = 4 * h + lt;
            const floatx4 binit = *(const floatx4*)&sb2f[nt * 16 + q * 4]; // broadcast
            floatx4 a = binit, b = binit;
            #pragma unroll
            for (int kb = 0; kb < 4; ++kb) {
                const bf16x8 wf = W2sv[(kb * 128 + nt * 16 + p) * 4 + q];
                a = __builtin_amdgcn_mfma_f32_16x16x32_bf16(wf, aha[kb], a, 0, 0, 0);
                b = __builtin_amdgcn_mfma_f32_16x16x32_bf16(wf, ahb[kb], b, 0, 0, 0);
            }
            accA[lt] = a; accB[lt] = b;
        }
        #pragma unroll
        for (int lt = 0; lt < 4; ++lt) {            // group a epilogue
            bf16x4 v;
            #pragma unroll
            for (int r = 0; r < 4; ++r) v[r] = (__bf16)fast_tanh(accA[lt][r]);
            *(bf16x4*)&T[p * PITCH_H + lt * 16 + q * 4] = v;
        }
        ah2a[2 * h]     = *(const bf16x8*)&T[p * PITCH_H + q * 8];
        ah2a[2 * h + 1] = *(const bf16x8*)&T[p * PITCH_H + 32 + q * 8];
        #pragma unroll
        for (int lt = 0; lt < 4; ++lt) {            // group b epilogue
            bf16x4 v;
            #pragma unroll
            for (int r = 0; r < 4; ++r) v[r] = (__bf16)fast_tanh(accB[lt][r]);
            *(bf16x4*)&T[p * PITCH_H + lt * 16 + q * 4] = v;
        }
        ah2b[2 * h]     = *(const bf16x8*)&T[p * PITCH_H + q * 8];
        ah2b[2 * h + 1] = *(const bf16x8*)&T[p * PITCH_H + 32 + q * 8];
    }

    // ---- GEMM3: dz^T = mfma(W3^T-frag, h2^T-frag, C=b3); float4 store ----
    floatx4 d3A = b3f, d3B = b3f;
    #pragma unroll
    for (int kb = 0; kb < 4; ++kb) {
        d3A = __builtin_amdgcn_mfma_f32_16x16x32_bf16(w3f[kb], ah2a[kb], d3A, 0, 0, 0);
        d3B = __builtin_amdgcn_mfma_f32_16x16x32_bf16(w3f[kb], ah2b[kb], d3B, 0, 0, 0);
    }
    if (q < 2) {
        *(floatx4*)(out + (size_t)(sbase + p) * 8 + q * 4) = d3A;
        *(floatx4*)(out + (size_t)(sbase + 16 + p) * 8 + q * 4) = d3B;
    }

    // a2 A-frags in-register: a2 = 1 - h2^2 (elementwise in k)
    bf16x8 aaA[4], aaB[4];
    #pragma unroll
    for (int kb = 0; kb < 4; ++kb) {
        #pragma unroll
        for (int j = 0; j < 8; ++j) {
            const float fa = (float)ah2a[kb][j];
            aaA[kb][j] = (__bf16)__builtin_fmaf(-fa, fa, 1.0f);
            const float fb = (float)ah2b[kb][j];
            aaB[kb][j] = (__bf16)__builtin_fmaf(-fb, fb, 1.0f);
        }
    }

    // ---- GEMM2: U^T = mfma(G-frag, a2^T-frag); U lands in same [hidden][sample]
    // mapping as a1c -> trace = scalar per lane, 2-shuffle reduce ----
    float trA = 0.f, trB = 0.f;
    #pragma unroll
    for (int nt = 0; nt < 8; ++nt) {
        floatx4 uA = {0.f, 0.f, 0.f, 0.f}, uB = {0.f, 0.f, 0.f, 0.f};
        #pragma unroll
        for (int kb = 0; kb < 4; ++kb) {
            const bf16x8 gf = GTsv[(kb * 128 + nt * 16 + p) * 4 + q];
            uA = __builtin_amdgcn_mfma_f32_16x16x32_bf16(gf, aaA[kb], uA, 0, 0, 0);
            uB = __builtin_amdgcn_mfma_f32_16x16x32_bf16(gf, aaB[kb], uB, 0, 0, 0);
        }
        #pragma unroll
        for (int r = 0; r < 4; ++r) {
            trA = __builtin_fmaf(a1c0[nt * 4 + r], uA[r], trA);
            trB = __builtin_fmaf(a1c1[nt * 4 + r], uB[r], trB);
        }
    }
    trA += __shfl_xor(trA, 16, 64);
    trA += __shfl_xor(trA, 32, 64);
    trB += __shfl_xor(trB, 16, 64);
    trB += __shfl_xor(trB, 32, 64);
    if (lane < 16) {
        out[(size_t)BATCH * 8 + sbase + p] = -trA;
        out[(size_t)BATCH * 8 + sbase + 16 + p] = -trB;
    }
}

extern "C" void kernel_launch(void* const* d_in, const int* in_sizes, int n_in,
                              void* d_out, int out_size, void* d_ws, size_t ws_size,
                              hipStream_t stream) {
    const float* z  = (const float*)d_in[0];
    // d_in[1] = logp_z (unused by the reference math)
    const float* t  = (const float*)d_in[2];
    const float* W1 = (const float*)d_in[3];
    const float* b1 = (const float*)d_in[4];
    const float* W2 = (const float*)d_in[5];
    const float* b2 = (const float*)d_in[6];
    const float* W3 = (const float*)d_in[7];
    const float* b3 = (const float*)d_in[8];
    __bf16* ws = (__bf16*)d_ws;
    float* out = (float*)d_out;

    prep_kernel<<<88, 256, 0, stream>>>(W1, W2, W3, b1, ws);
    cnf_main<<<1024, 256, 0, stream>>>(z, t, b1, b2, b3, ws, out);
}

// Round 12
// 88.040 us; speedup vs baseline: 1.1053x; 1.0217x over previous
//
#include <hip/hip_runtime.h>
#include <hip/hip_bf16.h>

#define BATCH 131072
#define PITCH_H 72   // half-tile row: 64 + 8 pad bf16 (144 B = 9x16B; rows stay 16B-aligned)

typedef __bf16 bf16x4 __attribute__((ext_vector_type(4)));
typedef __bf16 bf16x8 __attribute__((ext_vector_type(8)));
typedef float floatx4 __attribute__((ext_vector_type(4)));

#define GLOBAL_AS __attribute__((address_space(1)))
#define LDS_AS __attribute__((address_space(3)))

__device__ __forceinline__ float fast_tanh(float x) {
    // tanh(x) = 1 - 2/(exp(2x)+1); exp overflow -> inf -> rcp -> 0 -> +1 (correct limit)
    float e = __expf(2.0f * x);
    return 1.0f - 2.0f * __builtin_amdgcn_rcpf(e + 1.0f);
}

// d_ws element layout (bf16):
// [0,16384)       W2s : frag-swizzled W2                (GEMM1)
// [16384,32768)   GTs : frag-swizzled G^T, G=W2*C^T     (GEMM2)
// [32768,36864)   W1s : frag-swizzled W1, K pad to 32; rows k=9,10 carry b1 hi/lo (GEMM0)
// [36864,38912)   W3s : frag-swizzled W3, N pad to 16   (GEMM3)
// swizzle: idx = ((kb*N + n)*4 + q)*8 + j  <->  M[k = kb*32 + q*8 + j][n]
// Operand-swap symmetry: A-frag of M^T == B-frag of M for mfma_16x16x32, so
// these fragments serve the transposed GEMMs with no prep change.

__global__ void prep_kernel(const float* __restrict__ W1,
                            const float* __restrict__ W2,
                            const float* __restrict__ W3,
                            const float* __restrict__ b1,
                            __bf16* __restrict__ ws) {
    int idx = blockIdx.x * 256 + threadIdx.x;
    if (idx < 16384) {
        int j = idx & 7, q = (idx >> 3) & 3, n = (idx >> 5) & 127, kb = idx >> 12;
        int k = kb * 32 + q * 8 + j;
        ws[idx] = (__bf16)W2[k * 128 + n];
        float c = 0.0f;
        #pragma unroll
        for (int d = 0; d < 8; ++d) c += W3[k * 8 + d] * W1[d * 128 + n];
        ws[16384 + idx] = (__bf16)(W2[n * 128 + k] * c);
    } else if (idx < 20480) {
        int t = idx - 16384;
        int j = t & 7, q = (t >> 3) & 3, n = t >> 5;   // kb==0 only
        int k = q * 8 + j;
        __bf16 v = (__bf16)0.0f;
        if (k < 9) v = (__bf16)W1[k * 128 + n];
        else if (k == 9) v = (__bf16)b1[n];                    // bias hi (x[9]=1)
        else if (k == 10) {                                    // bias lo (x[10]=1)
            float hi = (float)(__bf16)b1[n];
            v = (__bf16)(b1[n] - hi);
        }
        ws[32768 + t] = v;
    } else if (idx < 22528) {
        int t = idx - 20480;
        int j = t & 7, q = (t >> 3) & 3, n = (t >> 5) & 15, kb = t >> 9;
        int k = kb * 32 + q * 8 + j;
        ws[36864 + t] = (n < 8) ? (__bf16)W3[k * 8 + n] : (__bf16)0.0f;
    }
}

// Structure rationale (rounds 0-11 evidence):
//  - R11 (operand-swap transposed GEMMs): best, cnf ~30us. Pipe inventories
//    (MFMA ~1us, VALU ~5us chip-wide) no longer explain the time; remaining
//    cost is per-block setup x 4 residency rounds: 64 KB L2 staging whose
//    ds_write vmcnt stalls ALSO blocked GEMM0 (in program order).
//  - THIS ROUND: (1) grid 512 x 2 its -> staging paid once per 256 samples,
//    one clean residency round; (2) global_load_lds DMA staging -> no
//    in-stream ds_write, GEMM0 genuinely overlaps the 64 KB copy; only the
//    __syncthreads before GEMM1 drains it; (3) z for it1 prefetched after
//    it0's GEMM0 (HBM latency hides under GEMM1+GEMM2); (4) b2 LDS write
//    moved after GEMM0.
//  - LDS = 32(W2)+32(GT)+9(tiles)+0.5(b2) = 73.5 KB -> 2 blocks/CU.
//  - launch_bounds(256,2) ONLY: budget-256 is the proven spill-free regime
//    (R0 128, R3 72, R7 128 VGPR). min-waves>=4 attrs -> 64-VGPR acc-split
//    + ~200 MB scratch spill (R1/R2). Watch: FETCH must stay ~5 MB.
__global__ __launch_bounds__(256, 2) void cnf_main(
        const float* __restrict__ z, const float* __restrict__ t_ptr,
        const float* __restrict__ b1g, const float* __restrict__ b2g,
        const float* __restrict__ b3g, const __bf16* __restrict__ ws,
        float* __restrict__ out) {
    __shared__ __bf16 sW2s[16384];                             // 32 KB
    __shared__ __bf16 sGTs[16384];                             // 32 KB
    __shared__ float sb2f[128];                                // 512 B
    __shared__ __align__(16) __bf16 tile[4][16 * PITCH_H];     // 9 KB

    const int tid = threadIdx.x;
    const int lane = tid & 63;
    const int w = tid >> 6;
    const int p = lane & 15;       // sample index (C/D col in all GEMMs)
    const int q = lane >> 4;       // quad (C/D row group)
    const float tval = t_ptr[0];

    // ---- hoisted scalar/frag loads (issue before DMA; GEMM0 needs them) ----
    const bf16x8* W1g = (const bf16x8*)(ws + 32768);
    const bf16x8* W3g = (const bf16x8*)(ws + 36864);
    bf16x8 w1f[8];
    #pragma unroll
    for (int nt = 0; nt < 8; ++nt) w1f[nt] = W1g[(nt * 16 + p) * 4 + q];
    bf16x8 w3f[4];
    #pragma unroll
    for (int kb = 0; kb < 4; ++kb) w3f[kb] = W3g[(kb * 16 + p) * 4 + q];
    floatx4 b3f = {0.f, 0.f, 0.f, 0.f};
    if (q < 2) b3f = *(const floatx4*)(b3g + q * 4);   // dz rows q*4+r (real d<8)
    const float b2v = (tid < 128) ? b2g[tid] : 0.0f;

    // z for it 0 (q==0 lanes; latency hides under DMA issue + GEMM0 prep)
    float4 zc0a, zc1a, zc0b, zc1b;
    {
        const int sb0 = blockIdx.x * 256 + w * 32;
        if (q == 0) {
            const float4* zp0 = (const float4*)(z + (size_t)(sb0 + p) * 8);
            const float4* zp1 = (const float4*)(z + (size_t)(sb0 + 16 + p) * 8);
            zc0a = zp0[0]; zc1a = zp0[1]; zc0b = zp1[0]; zc1b = zp1[1];
        }
    }

    // ---- async DMA staging of W2 + GT (linear, wave-uniform base + lane*16) ----
    {
        const uint4* srcW2v = (const uint4*)ws;
        const uint4* srcGTv = (const uint4*)(ws + 16384);
        uint4* dstW2v = (uint4*)sW2s;
        uint4* dstGTv = (uint4*)sGTs;
        #pragma unroll
        for (int i = 0; i < 8; ++i) {
            const int idx = tid + i * 256;
            const int wbase = w * 64 + i * 256;   // wave-uniform uint4 index
            __builtin_amdgcn_global_load_lds(
                (const GLOBAL_AS uint4*)(srcW2v + idx),
                (LDS_AS uint4*)(dstW2v + wbase), 16, 0, 0);
            __builtin_amdgcn_global_load_lds(
                (const GLOBAL_AS uint4*)(srcGTv + idx),
                (LDS_AS uint4*)(dstGTv + wbase), 16, 0, 0);
        }
    }

    __bf16* T = tile[w];
    const bf16x8* W2sv = (const bf16x8*)sW2s;
    const bf16x8* GTsv = (const bf16x8*)sGTs;

    float4 zn0a, zn1a, zn0b, zn1b;   // prefetched z for it 1

    #pragma unroll
    for (int it = 0; it < 2; ++it) {
        const int sbase = blockIdx.x * 256 + it * 128 + w * 32;

        // ---- build B-frags of X^T: lane holds x[sample p][k=q*8+j] ----
        bf16x8 ax0, ax1;
        #pragma unroll
        for (int j = 0; j < 8; ++j) { ax0[j] = (__bf16)0.0f; ax1[j] = (__bf16)0.0f; }
        if (q == 0) {
            ax0[0] = (__bf16)zc0a.x; ax0[1] = (__bf16)zc0a.y;
            ax0[2] = (__bf16)zc0a.z; ax0[3] = (__bf16)zc0a.w;
            ax0[4] = (__bf16)zc1a.x; ax0[5] = (__bf16)zc1a.y;
            ax0[6] = (__bf16)zc1a.z; ax0[7] = (__bf16)zc1a.w;
            ax1[0] = (__bf16)zc0b.x; ax1[1] = (__bf16)zc0b.y;
            ax1[2] = (__bf16)zc0b.z; ax1[3] = (__bf16)zc0b.w;
            ax1[4] = (__bf16)zc1b.x; ax1[5] = (__bf16)zc1b.y;
            ax1[6] = (__bf16)zc1b.z; ax1[7] = (__bf16)zc1b.w;
        } else if (q == 1) {
            ax0[0] = (__bf16)tval; ax0[1] = (__bf16)1.0f; ax0[2] = (__bf16)1.0f;
            ax1[0] = (__bf16)tval; ax1[1] = (__bf16)1.0f; ax1[2] = (__bf16)1.0f;
        }

        // ---- GEMM0: h1^T = mfma(W1^T-frag, X^T-frag); bias via K-slots ----
        float a1c0[32], a1c1[32];
        bf16x8 aha[4], ahb[4];
        #pragma unroll
        for (int h = 0; h < 2; ++h) {
            floatx4 accA[4], accB[4];
            #pragma unroll
            for (int lt = 0; lt < 4; ++lt) {
                const floatx4 zz = {0.f, 0.f, 0.f, 0.f};
                accA[lt] = __builtin_amdgcn_mfma_f32_16x16x32_bf16(w1f[4 * h + lt], ax0, zz, 0, 0, 0);
                accB[lt] = __builtin_amdgcn_mfma_f32_16x16x32_bf16(w1f[4 * h + lt], ax1, zz, 0, 0, 0);
            }
            #pragma unroll
            for (int lt = 0; lt < 4; ++lt) {            // group a epilogue
                bf16x4 v;
                #pragma unroll
                for (int r = 0; r < 4; ++r) {
                    const float h1 = fast_tanh(accA[lt][r]);
                    a1c0[(4 * h + lt) * 4 + r] = __builtin_fmaf(-h1, h1, 1.0f);
                    v[r] = (__bf16)h1;
                }
                *(bf16x4*)&T[p * PITCH_H + lt * 16 + q * 4] = v;   // contiguous b64
            }
            // wave-private in-order DS: write->read round-trip safe, no barrier
            aha[2 * h]     = *(const bf16x8*)&T[p * PITCH_H + q * 8];
            aha[2 * h + 1] = *(const bf16x8*)&T[p * PITCH_H + 32 + q * 8];
            #pragma unroll
            for (int lt = 0; lt < 4; ++lt) {            // group b epilogue (tile reused)
                bf16x4 v;
                #pragma unroll
                for (int r = 0; r < 4; ++r) {
                    const float h1 = fast_tanh(accB[lt][r]);
                    a1c1[(4 * h + lt) * 4 + r] = __builtin_fmaf(-h1, h1, 1.0f);
                    v[r] = (__bf16)h1;
                }
                *(bf16x4*)&T[p * PITCH_H + lt * 16 + q * 4] = v;
            }
            ahb[2 * h]     = *(const bf16x8*)&T[p * PITCH_H + q * 8];
            ahb[2 * h + 1] = *(const bf16x8*)&T[p * PITCH_H + 32 + q * 8];
        }

        if (it == 0) {
            // prefetch z for it 1: latency hides under GEMM1+GEMM2
            if (q == 0) {
                const int sb1i = blockIdx.x * 256 + 128 + w * 32;
                const float4* zp0 = (const float4*)(z + (size_t)(sb1i + p) * 8);
                const float4* zp1 = (const float4*)(z + (size_t)(sb1i + 16 + p) * 8);
                zn0a = zp0[0]; zn1a = zp0[1]; zn0b = zp1[0]; zn1b = zp1[1];
            }
            // b2 -> LDS, then the single barrier (drains staging DMA via vmcnt)
            if (tid < 128) sb2f[tid] = b2v;
            __syncthreads();
        }

        // ---- GEMM1: h2^T = mfma(W2^T-frag, h1^T-frag, C=b2); shared W2 reads ----
        bf16x8 ah2a[4], ah2b[4];
        #pragma unroll
        for (int h = 0; h < 2; ++h) {
            floatx4 accA[4], accB[4];
            #pragma unroll
            for (int lt = 0; lt < 4; ++lt) {
                const int nt = 4 * h + lt;
                const floatx4 binit = *(const floatx4*)&sb2f[nt * 16 + q * 4]; // broadcast
                floatx4 a = binit, b = binit;
                #pragma unroll
                for (int kb = 0; kb < 4; ++kb) {
                    const bf16x8 wf = W2sv[(kb * 128 + nt * 16 + p) * 4 + q];
                    a = __builtin_amdgcn_mfma_f32_16x16x32_bf16(wf, aha[kb], a, 0, 0, 0);
                    b = __builtin_amdgcn_mfma_f32_16x16x32_bf16(wf, ahb[kb], b, 0, 0, 0);
                }
                accA[lt] = a; accB[lt] = b;
            }
            #pragma unroll
            for (int lt = 0; lt < 4; ++lt) {            // group a epilogue
                bf16x4 v;
                #pragma unroll
                for (int r = 0; r < 4; ++r) v[r] = (__bf16)fast_tanh(accA[lt][r]);
                *(bf16x4*)&T[p * PITCH_H + lt * 16 + q * 4] = v;
            }
            ah2a[2 * h]     = *(const bf16x8*)&T[p * PITCH_H + q * 8];
            ah2a[2 * h + 1] = *(const bf16x8*)&T[p * PITCH_H + 32 + q * 8];
            #pragma unroll
            for (int lt = 0; lt < 4; ++lt) {            // group b epilogue
                bf16x4 v;
                #pragma unroll
                for (int r = 0; r < 4; ++r) v[r] = (__bf16)fast_tanh(accB[lt][r]);
                *(bf16x4*)&T[p * PITCH_H + lt * 16 + q * 4] = v;
            }
            ah2b[2 * h]     = *(const bf16x8*)&T[p * PITCH_H + q * 8];
            ah2b[2 * h + 1] = *(const bf16x8*)&T[p * PITCH_H + 32 + q * 8];
        }

        // ---- GEMM3: dz^T = mfma(W3^T-frag, h2^T-frag, C=b3); float4 store ----
        floatx4 d3A = b3f, d3B = b3f;
        #pragma unroll
        for (int kb = 0; kb < 4; ++kb) {
            d3A = __builtin_amdgcn_mfma_f32_16x16x32_bf16(w3f[kb], ah2a[kb], d3A, 0, 0, 0);
            d3B = __builtin_amdgcn_mfma_f32_16x16x32_bf16(w3f[kb], ah2b[kb], d3B, 0, 0, 0);
        }
        if (q < 2) {
            *(floatx4*)(out + (size_t)(sbase + p) * 8 + q * 4) = d3A;
            *(floatx4*)(out + (size_t)(sbase + 16 + p) * 8 + q * 4) = d3B;
        }

        // a2 A-frags in-register: a2 = 1 - h2^2 (elementwise in k)
        bf16x8 aaA[4], aaB[4];
        #pragma unroll
        for (int kb = 0; kb < 4; ++kb) {
            #pragma unroll
            for (int j = 0; j < 8; ++j) {
                const float fa = (float)ah2a[kb][j];
                aaA[kb][j] = (__bf16)__builtin_fmaf(-fa, fa, 1.0f);
                const float fb = (float)ah2b[kb][j];
                aaB[kb][j] = (__bf16)__builtin_fmaf(-fb, fb, 1.0f);
            }
        }

        // ---- GEMM2: U^T = mfma(G-frag, a2^T-frag); trace scalar/lane ----
        float trA = 0.f, trB = 0.f;
        #pragma unroll
        for (int nt = 0; nt < 8; ++nt) {
            floatx4 uA = {0.f, 0.f, 0.f, 0.f}, uB = {0.f, 0.f, 0.f, 0.f};
            #pragma unroll
            for (int kb = 0; kb < 4; ++kb) {
                const bf16x8 gf = GTsv[(kb * 128 + nt * 16 + p) * 4 + q];
                uA = __builtin_amdgcn_mfma_f32_16x16x32_bf16(gf, aaA[kb], uA, 0, 0, 0);
                uB = __builtin_amdgcn_mfma_f32_16x16x32_bf16(gf, aaB[kb], uB, 0, 0, 0);
            }
            #pragma unroll
            for (int r = 0; r < 4; ++r) {
                trA = __builtin_fmaf(a1c0[nt * 4 + r], uA[r], trA);
                trB = __builtin_fmaf(a1c1[nt * 4 + r], uB[r], trB);
            }
        }
        trA += __shfl_xor(trA, 16, 64);
        trA += __shfl_xor(trA, 32, 64);
        trB += __shfl_xor(trB, 16, 64);
        trB += __shfl_xor(trB, 32, 64);
        if (lane < 16) {
            out[(size_t)BATCH * 8 + sbase + p] = -trA;
            out[(size_t)BATCH * 8 + sbase + 16 + p] = -trB;
        }

        // rotate prefetched z into current
        if (it == 0) { zc0a = zn0a; zc1a = zn1a; zc0b = zn0b; zc1b = zn1b; }
    }
}

extern "C" void kernel_launch(void* const* d_in, const int* in_sizes, int n_in,
                              void* d_out, int out_size, void* d_ws, size_t ws_size,
                              hipStream_t stream) {
    const float* z  = (const float*)d_in[0];
    // d_in[1] = logp_z (unused by the reference math)
    const float* t  = (const float*)d_in[2];
    const float* W1 = (const float*)d_in[3];
    const float* b1 = (const float*)d_in[4];
    const float* W2 = (const float*)d_in[5];
    const float* b2 = (const float*)d_in[6];
    const float* W3 = (const float*)d_in[7];
    const float* b3 = (const float*)d_in[8];
    __bf16* ws = (__bf16*)d_ws;
    float* out = (float*)d_out;

    prep_kernel<<<88, 256, 0, stream>>>(W1, W2, W3, b1, ws);
    cnf_main<<<512, 256, 0, stream>>>(z, t, b1, b2, b3, ws, out);
}